// Round 7
// baseline (88.929 us; speedup 1.0000x reference)
//
#include <hip/hip_runtime.h>

// PrRoIPool2D forward, MI355X. B=8, C=256, H=W=48, R=300, 7x7 bins, scale=1/16.
// R17: SINGLE kernel, zero prep. R16 post-mortem: main is round-trip-latency
// bound; the prm table costs a launch+gap (~4-6us) but saves zero round trips
// (table read == roi read, 1 trip either way). So:
//  - each wave reads its 20B roi row (wave-uniform -> s_loads), computes
//    bounds, issues ALL 6 feature float4 loads immediately, then computes its
//    per-lane wx/wy weights (~24 hat_int, ~120 VALU cy) UNDER the load shadow.
//  - R14 structure kept (best measured): wave = (r, 2 channels), 9600
//    independent waves, barrier-free, intra-wave lgkmcnt fences only.
//  - linear LDS (R12/R16: swizzle off critical path), immediate-offset reads.
//  - launch_bounds(256,6): 6 blocks/CU x 4 waves = 24 waves/CU; ~70 VGPR.
//  - grid dim3(32,300): linear id % 8 == blockIdx.x % 8 -> channel->XCD
//    partition, 2.36 MB L2 working set per XCD.
// Numerics: bounds/weight expressions form-identical to R10-R16 prep (same
// fmaxf//7.0f/floorf/hat_int forms, same tap order x ii=0..5, y jj=0..5,
// then *inv_area) -> bit-identical outputs, absmax unchanged.

#define PH 7
#define PW 7
#define NBINS 49
#define SCALE 0.0625f
#define CH 256
#define FH 48
#define FW 48
#define RNUM 300
#define PATCHF (23 * 56)         // [j<23][i<28][c2] linear, 5152 B
#define RSF 328                  // 7*23*2 = 322, padded

__device__ __forceinline__ float hat_int(float x, float g) {
    float t = x - (g - 1.0f);
    if (t <= 0.0f) return 0.0f;
    if (t <= 1.0f) return 0.5f * t * t;
    if (t <= 2.0f) { float u = 2.0f - t; return 1.0f - 0.5f * u * u; }
    return 1.0f;
}

__global__ __launch_bounds__(256, 6)
void prroi_one(const float* __restrict__ feat,
               const float* __restrict__ rois,
               float* __restrict__ out) {
    const int wv   = threadIdx.x >> 6;          // wave 0..3
    const int lane = threadIdx.x & 63;
    const int r    = blockIdx.y;                // 0..299
    const int cpr  = blockIdx.x * 4 + wv;       // channel pair 0..127
    const int c0   = cpr * 2;

    __shared__ float lds[4][PATCHF + RSF];      // 25856 B -> 6 blocks/CU
    float* patch = lds[wv];
    float* rsw   = lds[wv] + PATCHF;

    // ---- trip 1: roi row (wave-uniform -> scalar loads) ----
    const float* roi = rois + r * 5;
    const float f0 = roi[0], f1 = roi[1], f2 = roi[2], f3 = roi[3], f4 = roi[4];
    const int   b  = (int)f0;
    const float x1 = f1 * SCALE, y1 = f2 * SCALE;
    const float x2 = f3 * SCALE, y2 = f4 * SCALE;
    const float roi_w = fmaxf(x2 - x1, 0.0f), roi_h = fmaxf(y2 - y1, 0.0f);
    const float bin_w = roi_w / (float)PW, bin_h = roi_h / (float)PH;
    const float area = bin_w * bin_h;
    const float ia   = (area > 0.0f) ? (1.0f / area) : 0.0f;

    const float ylo = fminf(y1, y2), yhi = fmaxf(y1, y2);
    const float xlo = fminf(x1, x2), xhi = fmaxf(x1, x2);
    const int j1 = min(FH - 1, (int)floorf(yhi) + 1);
    const int i1 = min(FW - 1, (int)floorf(xhi) + 1);
    const int J0 = min(max(0, (int)floorf(ylo) - 1), FH - 6);
    const int I0 = min(max(0, (int)floorf(xlo) - 1) & ~3, FW - 8);
    const int JROWS = min(FH - J0, max(j1 - J0 + 1, 6));        // 6..23
    int NI4 = min(((i1 - I0) >> 2) + 1, (FW - I0) >> 2);
    NI4 = max(NI4, 2);                                           // 2..7

    // ---- trip 2: issue ALL feature loads now (latency shadow starts) ----
    const int NU = JROWS << 3;                  // (j, i4) units, i4 in 0..7
    const float* fb = feat + (size_t)(b * CH + c0) * (FH * FW);
    bool act_[3]; int dst_[3];
    float4 pc0[3], pc1[3];
#pragma unroll
    for (int s = 0; s < 3; ++s) {
        const int u  = lane + (s << 6);
        const int j  = u >> 3, i4 = u & 7;
        const bool a = (u < NU) && (i4 < NI4);
        act_[s] = a;
        dst_[s] = j * 56 + 8 * i4;
        if (a) {
            const float* src = fb + (size_t)(J0 + j) * FW + I0 + 4 * i4;
            pc0[s] = *(const float4*)(src);              // channel c0
            pc1[s] = *(const float4*)(src + FH * FW);    // channel c0+1
        }
    }

    // ---- weights in registers, computed UNDER the load shadow ----
    const int  pwA = lane >> 3, jsl = lane & 7;
    const bool actA = lane < 56;
    float wx0 = 0, wx1 = 0, wx2 = 0, wx3 = 0, wx4 = 0, wx5 = 0;
    int biA = 0;
    if (actA) {
        const float xa = x1 + pwA * bin_w, xb = xa + bin_w;
        const int base = min(max((int)floorf(xa) - 1, I0), I0 + 4 * NI4 - 6);
        biA = base - I0;
        wx0 = hat_int(xb, (float)(base + 0)) - hat_int(xa, (float)(base + 0));
        wx1 = hat_int(xb, (float)(base + 1)) - hat_int(xa, (float)(base + 1));
        wx2 = hat_int(xb, (float)(base + 2)) - hat_int(xa, (float)(base + 2));
        wx3 = hat_int(xb, (float)(base + 3)) - hat_int(xa, (float)(base + 3));
        wx4 = hat_int(xb, (float)(base + 4)) - hat_int(xa, (float)(base + 4));
        wx5 = hat_int(xb, (float)(base + 5)) - hat_int(xa, (float)(base + 5));
    }
    const bool actB = lane < NBINS;
    float wy0 = 0, wy1 = 0, wy2 = 0, wy3 = 0, wy4 = 0, wy5 = 0;
    int pwB = 0, bjB = 0;
    if (actB) {
        const int ph = lane / 7;
        pwB = lane - ph * 7;
        const float ya = y1 + ph * bin_h, yb = ya + bin_h;
        const int base = min(max((int)floorf(ya) - 1, J0), J0 + JROWS - 6);
        bjB = base - J0;
        wy0 = hat_int(yb, (float)(base + 0)) - hat_int(ya, (float)(base + 0));
        wy1 = hat_int(yb, (float)(base + 1)) - hat_int(ya, (float)(base + 1));
        wy2 = hat_int(yb, (float)(base + 2)) - hat_int(ya, (float)(base + 2));
        wy3 = hat_int(yb, (float)(base + 3)) - hat_int(ya, (float)(base + 3));
        wy4 = hat_int(yb, (float)(base + 4)) - hat_int(ya, (float)(base + 4));
        wy5 = hat_int(yb, (float)(base + 5)) - hat_int(ya, (float)(base + 5));
    }

    // ---- stage patch [j][i][c2] (vmcnt waits land here, mostly absorbed) ----
#pragma unroll
    for (int s = 0; s < 3; ++s) {
        if (act_[s]) {
            float* d = patch + dst_[s];
            *(float4*)(d + 0) = make_float4(pc0[s].x, pc1[s].x, pc0[s].y, pc1[s].y);
            *(float4*)(d + 4) = make_float4(pc0[s].z, pc1[s].z, pc0[s].w, pc1[s].w);
        }
    }
    asm volatile("s_waitcnt lgkmcnt(0)" ::: "memory");

    // ---- PA: rs[pw][jr][c2] = sum_i wx * patch (linear, imm offsets) ----
    if (actA) {
        for (int jr = jsl; jr < JROWS; jr += 8) {
            const float* row = patch + jr * 56 + 2 * biA;
            const float2 v0 = *(const float2*)(row + 0);
            const float2 v1 = *(const float2*)(row + 2);
            const float2 v2 = *(const float2*)(row + 4);
            const float2 v3 = *(const float2*)(row + 6);
            const float2 v4 = *(const float2*)(row + 8);
            const float2 v5 = *(const float2*)(row + 10);
            float ax = 0.0f, ay = 0.0f;
            ax += wx0 * v0.x; ay += wx0 * v0.y;
            ax += wx1 * v1.x; ay += wx1 * v1.y;
            ax += wx2 * v2.x; ay += wx2 * v2.y;
            ax += wx3 * v3.x; ay += wx3 * v3.y;
            ax += wx4 * v4.x; ay += wx4 * v4.y;
            ax += wx5 * v5.x; ay += wx5 * v5.y;
            *(float2*)&rsw[(pwA * 23 + jr) * 2] = make_float2(ax, ay);
        }
    }
    asm volatile("s_waitcnt lgkmcnt(0)" ::: "memory");

    // ---- PB: out[bin][c2] = sum_j wy * rs ----
    if (actB) {
        const float* rb = rsw + (pwB * 23 + bjB) * 2;
        const float2 u0 = *(const float2*)(rb + 0);
        const float2 u1 = *(const float2*)(rb + 2);
        const float2 u2 = *(const float2*)(rb + 4);
        const float2 u3 = *(const float2*)(rb + 6);
        const float2 u4 = *(const float2*)(rb + 8);
        const float2 u5 = *(const float2*)(rb + 10);
        float ax = 0.0f, ay = 0.0f;
        ax += wy0 * u0.x; ay += wy0 * u0.y;
        ax += wy1 * u1.x; ay += wy1 * u1.y;
        ax += wy2 * u2.x; ay += wy2 * u2.y;
        ax += wy3 * u3.x; ay += wy3 * u3.y;
        ax += wy4 * u4.x; ay += wy4 * u4.y;
        ax += wy5 * u5.x; ay += wy5 * u5.y;
        float* o = out + ((size_t)r * CH + c0) * NBINS + lane;
        o[0]     = ax * ia;                     // channel c0
        o[NBINS] = ay * ia;                     // channel c0+1
    }
}

extern "C" void kernel_launch(void* const* d_in, const int* in_sizes, int n_in,
                              void* d_out, int out_size, void* d_ws, size_t ws_size,
                              hipStream_t stream) {
    const float* feat = (const float*)d_in[0];
    const float* rois = (const float*)d_in[1];
    float* out = (float*)d_out;
    (void)d_ws; (void)ws_size;

    prroi_one<<<dim3(32, RNUM), 256, 0, stream>>>(feat, rois, out);
}